// Round 8
// baseline (121.859 us; speedup 1.0000x reference)
//
#include <hip/hip_runtime.h>
#include <hip/hip_bf16.h>
#include <math.h>
#include <stdint.h>

#define BATCH 2
#define NH 12
#define SEQ 2048
#define HD 64
#define TQ 64
#define TK 64
#define NHEADS (BATCH*NH)
#define NIT (SEQ / TK)

typedef short bf16x8 __attribute__((ext_vector_type(8)));
typedef float f32x4 __attribute__((ext_vector_type(4)));
typedef float f32x16 __attribute__((ext_vector_type(16)));
typedef unsigned short us4_t __attribute__((ext_vector_type(4)));
typedef unsigned short us8_t __attribute__((ext_vector_type(8)));
typedef unsigned int u32x4 __attribute__((ext_vector_type(4)));

#if __has_builtin(__builtin_amdgcn_exp2f)
#define EXP2F(x) __builtin_amdgcn_exp2f(x)
#else
#define EXP2F(x) exp2f(x)
#endif

static __device__ __forceinline__ unsigned short f2bf(float f) {
    unsigned int u = __float_as_uint(f);
    u += 0x7fffu + ((u >> 16) & 1u);   // RTNE
    return (unsigned short)(u >> 16);
}

static __device__ __forceinline__ unsigned int pack2bf(float a, float b) {
    __hip_bfloat162 v = __float22bfloat162_rn(float2{a, b});
    return *(unsigned int*)&v;          // low short = a
}

static __device__ __forceinline__ void async_cp16(const void* g, void* l) {
    __builtin_amdgcn_global_load_lds(
        (const __attribute__((address_space(1))) void*)g,
        (__attribute__((address_space(3))) void*)(uintptr_t)l,
        16, 0, 0);
}

// Conflict-free 64x64-bf16 tile layout: 32 row-pairs x 256B, 16 positions of
// 16B, pos = ((r&1)*8 | c) ^ ((r>>1)&15).
static __device__ __forceinline__ int tile_off(int r, int c) {   // shorts, c 0..7
    int rp  = r >> 1;
    int pos = (((r & 1) << 3) | c) ^ (rp & 15);
    return rp * 128 + pos * 8;
}

// ---- pre-pass (R14: V only — K conversion is fused into fa_main's staging).
// V -> bf16 transposed [bh][d][s'] where s' = s with bits 2<->3 swapped inside
// each 32-block (pi-permutation that makes the S^T C-layout register order
// equal the PV A-operand order).
__global__ __launch_bounds__(256)
void prep_v(const float* __restrict__ V, unsigned short* __restrict__ Vtb) {
    __shared__ unsigned short T[64][66];
    const int bh = blockIdx.x >> 5;
    const int s0 = (blockIdx.x & 31) * 64;
    const int tid = threadIdx.x;
    const size_t off = ((size_t)bh * SEQ + s0) * HD;

    #pragma unroll
    for (int u = 0; u < 4; ++u) {                 // V: dense loads -> padded LDS
        int idx = u * 1024 + tid * 4;
        int r = idx >> 6, col = idx & 63;
        float4 a = *(const float4*)&V[off + idx];
        *(unsigned int*)&T[r][col]     = pack2bf(a.x, a.y);
        *(unsigned int*)&T[r][col + 2] = pack2bf(a.z, a.w);
    }
    __syncthreads();
    unsigned short* Vdst = Vtb + (size_t)bh * HD * SEQ;
    const int g = tid & 7, dd = tid >> 3;         // dd 0..31
    #pragma unroll
    for (int h = 0; h < 2; ++h) {
        int d = dd + 32 * h;
        us8_t r8;
        #pragma unroll
        for (int j = 0; j < 8; ++j) {
            // pi: swap bits 2,3 of the 64-local column index (g*8 + j)
            int src = ((g >> 1) << 4) + ((j >> 2) << 3) + ((g & 1) << 2) + (j & 3);
            r8[j] = T[src][d];
        }
        *(us8_t*)&Vdst[(size_t)d * SEQ + s0 + g * 8] = r8;
    }
}

// ---------------- main flash-attention kernel (32x32x16 MFMA) ----------------
// R14 = R13 (tri-buffer, prefetch distance 2, deferred-PV FIN in the ds_read
// shadow) with the K pre-pass ELIMINATED: K is staged straight from the f32
// input. The staging swizzle was already a pre-swizzled PER-LANE global
// address (kG0/kG1), so each lane loads its 8 f32 (2x float4, coalesced:
// 16-lane groups cover contiguous 512B), converts via pack2bf (same RTNE as
// the old prep -> bit-identical), and ds_write_b128's to the exact slot the
// old global_load_lds filled (dst*2 + lane*16). 2-stage K pipeline: load
// K(t+1) f32 after barrier(t), cvt+ds_write at end of iter t, consume at t+1
// (write target buf (t+1)%3 = tile t-2's buffer, reads done before
// barrier(t-1) < write at t; write drained by lgkmcnt(0)+barrier at t+1).
// V keeps async_cp16 at distance 2. The compiler's auto-vmcnt for the kr
// registers each iteration transitively retires all older VMEM (incl. V cps),
// so vmcnt(2) at the top is belt-and-braces. + s_setprio around MFMA clusters.
__global__ __launch_bounds__(256, 3)
void fa_main(const float* __restrict__ Q, const float* __restrict__ K,
             const unsigned short* __restrict__ Vtb,
             float* __restrict__ O, float qs) {
    const int x  = blockIdx.x & 7;
    const int t  = blockIdx.x >> 3;
    const int bh = x + 8 * (t % 3);
    const int qt = t / 3;
    const int q0 = qt * TQ;

    // 3 buffers x (K 8KB + V 8KB) + Lsum/Linv
    __shared__ __align__(16) unsigned char SH[49664];
    float* Lsum = (float*)(SH + 49152);                    // 64 f32
    float* Linv = (float*)(SH + 49408);                    // 64 f32
    float* ORed = (float*)SH;                              // 64x64 f32 overlay (buf0)
    unsigned short* QS = (unsigned short*)(SH + 32768);    // Q staging (buf2 K half)

    const int tid  = threadIdx.x;
    const int w    = tid >> 6;
    const int mt   = w >> 1;
    const int nt   = w & 1;
    const int lane = tid & 63;
    const int l31  = lane & 31;
    const int hi   = lane >> 5;

    const float*          Qh  = Q   + ((size_t)bh * SEQ + q0) * HD;
    const float*          KhF = K   + (size_t)bh * SEQ * HD;
    const unsigned short* Vh  = Vtb + (size_t)bh * HD * SEQ;

    // ---- per-lane staging source offsets (loop-invariant) ----
    int rS[2], cS[2];
    #pragma unroll
    for (int i = 0; i < 2; ++i) {
        int rp = w * 8 + 4 * i + (lane >> 4);
        int lc = (lane & 15) ^ (rp & 15);
        rS[i] = 2 * rp + (lc >> 3);
        cS[i] = lc & 7;
    }
    const int dst0 = (w * 8 + 0) * 128, dst1 = (w * 8 + 4) * 128;  // shorts
    const size_t kG0 = (size_t)rS[0] * HD  + cS[0] * 8;   // element index (f32 now)
    const size_t kG1 = (size_t)rS[1] * HD  + cS[1] * 8;
    const size_t vG0 = (size_t)rS[0] * SEQ + cS[0] * 8;
    const size_t vG1 = (size_t)rS[1] * SEQ + cS[1] * 8;
    const int ldsK0 = dst0 + lane * 8;   // shorts: byte dst0*2 + lane*16
    const int ldsK1 = dst1 + lane * 8;

    // K f32 -> bf16 staging of one tile into LDS buffer `Kn`
    auto stageK = [&](const float4& a0, const float4& a1,
                      const float4& b0f, const float4& b1f, unsigned short* Kn) {
        u32x4 w0 = { pack2bf(a0.x, a0.y), pack2bf(a0.z, a0.w),
                     pack2bf(a1.x, a1.y), pack2bf(a1.z, a1.w) };
        u32x4 w1 = { pack2bf(b0f.x, b0f.y), pack2bf(b0f.z, b0f.w),
                     pack2bf(b1f.x, b1f.y), pack2bf(b1f.z, b1f.w) };
        *(u32x4*)&Kn[ldsK0] = w0;
        *(u32x4*)&Kn[ldsK1] = w1;
    };

    // ---- prologue ----
    // tile 0: K f32 loads + V cp -> buf0 ; tile 1 V cp -> buf1 ; Q -> QS(buf2)
    float4 ka0 = *(const float4*)&KhF[kG0];
    float4 ka1 = *(const float4*)&KhF[kG0 + 4];
    float4 kb0 = *(const float4*)&KhF[kG1];
    float4 kb1 = *(const float4*)&KhF[kG1 + 4];
    {
        unsigned short* V0 = (unsigned short*)(SH + 8192);
        async_cp16(Vh + vG0, &V0[dst0]);
        async_cp16(Vh + vG1, &V0[dst1]);
        unsigned short* V1 = (unsigned short*)(SH + 16384 + 8192);
        async_cp16(Vh + (size_t)TK + vG0, &V1[dst0]);
        async_cp16(Vh + (size_t)TK + vG1, &V1[dst1]);
    }
    #pragma unroll
    for (int u = 0; u < 4; ++u) {
        int idx = u * 1024 + tid * 4;
        int r = idx >> 6, col = idx & 63;
        float4 a = *(const float4*)&Qh[idx];
        uint2 pk = { pack2bf(a.x * qs, a.y * qs), pack2bf(a.z * qs, a.w * qs) };
        *(uint2*)&QS[tile_off(r, col >> 3) + (col & 7)] = pk;
    }
    stageK(ka0, ka1, kb0, kb1, (unsigned short*)SH);   // K(0) -> buf0
    __syncthreads();   // Q staged + tile0 K/V resident (full drain; prologue only)

    // ---- Q B-fragments -> registers; then QS (buf2 K half) is free ----
    bf16x8 qf[4];
    #pragma unroll
    for (int s = 0; s < 4; ++s)
        qf[s] = *(const bf16x8*)&QS[tile_off(mt * 32 + l31, s * 2 + hi)];
    __syncthreads();

    // ---- hoisted fragment LDS offsets ----
    int kOffL[4], vOffL[2][2];
    #pragma unroll
    for (int s = 0; s < 4; ++s) kOffL[s] = tile_off(nt * 32 + l31, s * 2 + hi);
    #pragma unroll
    for (int dt = 0; dt < 2; ++dt)
        #pragma unroll
        for (int ks = 0; ks < 2; ++ks)
            vOffL[dt][ks] = tile_off(dt * 32 + l31, nt * 4 + ks * 2 + hi);

    f32x16 o[2];
    o[0] = (f32x16)(0.f);
    o[1] = (f32x16)(0.f);
    float lsum = 0.f;

    // deferred finish of a tile: exp2 + pack + PV + lsum (all register-local)
    auto FIN = [&](const f32x16& sp, const bf16x8 (&vp)[2][2]) {
        float e0[8], e1[8];
        #pragma unroll
        for (int r = 0; r < 8; ++r) e0[r] = EXP2F(sp[r]);
        #pragma unroll
        for (int r = 0; r < 8; ++r) e1[r] = EXP2F(sp[8 + r]);
        union { u32x4 d; bf16x8 h; } pu0, pu1;
        pu0.d = (u32x4){ pack2bf(e0[0], e0[1]), pack2bf(e0[2], e0[3]),
                         pack2bf(e0[4], e0[5]), pack2bf(e0[6], e0[7]) };
        pu1.d = (u32x4){ pack2bf(e1[0], e1[1]), pack2bf(e1[2], e1[3]),
                         pack2bf(e1[4], e1[5]), pack2bf(e1[6], e1[7]) };
        bf16x8 pf0 = pu0.h, pf1 = pu1.h;
        __builtin_amdgcn_s_setprio(1);
        o[0] = __builtin_amdgcn_mfma_f32_32x32x16_bf16(pf0, vp[0][0], o[0], 0, 0, 0);
        o[1] = __builtin_amdgcn_mfma_f32_32x32x16_bf16(pf0, vp[1][0], o[1], 0, 0, 0);
        o[0] = __builtin_amdgcn_mfma_f32_32x32x16_bf16(pf1, vp[0][1], o[0], 0, 0, 0);
        o[1] = __builtin_amdgcn_mfma_f32_32x32x16_bf16(pf1, vp[1][1], o[1], 0, 0, 0);
        __builtin_amdgcn_s_setprio(0);
        float t0 = ((e0[0] + e0[1]) + (e0[2] + e0[3]))
                 + ((e0[4] + e0[5]) + (e0[6] + e0[7]));
        float t1 = ((e1[0] + e1[1]) + (e1[2] + e1[3]))
                 + ((e1[4] + e1[5]) + (e1[6] + e1[7]));
        lsum += t0 + t1;
    };

    unsigned int b0 = 0, b1 = 16384, b2 = 32768;   // rotating buffer byte offsets

    // pipeline state: scores + V fragments of the previous tile
    f32x16 scp;
    bf16x8 vfp[2][2];

    // ---- peeled iteration 0 (tile 0 resident, all waves synced) ----
    {
        const unsigned short* Ks = (const unsigned short*)(SH + b0);
        const unsigned short* Vs = (const unsigned short*)(SH + b0 + 8192);
        bf16x8 kfc[4];
        #pragma unroll
        for (int s = 0; s < 4; ++s) kfc[s] = *(const bf16x8*)&Ks[kOffL[s]];
        #pragma unroll
        for (int dt = 0; dt < 2; ++dt)
            #pragma unroll
            for (int ks = 0; ks < 2; ++ks)
                vfp[dt][ks] = *(const bf16x8*)&Vs[vOffL[dt][ks]];

        // K(1) f32 loads; V(2) cp into buf2 V-half (QS region is dead now)
        ka0 = *(const float4*)&KhF[(size_t)TK * HD + kG0];
        ka1 = *(const float4*)&KhF[(size_t)TK * HD + kG0 + 4];
        kb0 = *(const float4*)&KhF[(size_t)TK * HD + kG1];
        kb1 = *(const float4*)&KhF[(size_t)TK * HD + kG1 + 4];
        {
            unsigned short* Vn = (unsigned short*)(SH + b2 + 8192);
            async_cp16(Vh + (size_t)2 * TK + vG0, &Vn[dst0]);
            async_cp16(Vh + (size_t)2 * TK + vG1, &Vn[dst1]);
        }

        f32x16 sc = (f32x16)(0.f);
        __builtin_amdgcn_s_setprio(1);
        #pragma unroll
        for (int s = 0; s < 4; ++s)
            sc = __builtin_amdgcn_mfma_f32_32x32x16_bf16(kfc[s], qf[s], sc, 0, 0, 0);
        __builtin_amdgcn_s_setprio(0);
        scp = sc;

        stageK(ka0, ka1, kb0, kb1, (unsigned short*)(SH + b1));  // K(1) -> buf1
        unsigned int btmp = b0; b0 = b1; b1 = b2; b2 = btmp;
    }

    // ---- main loop: iter t = {ds_reads(t) -> issue K(t+1)/V(t+2) ->
    //                           FIN(t-1) -> QK(t) -> cvt+write K(t+1)} ----
    #pragma unroll 2
    for (int it = 1; it < NIT; ++it) {
        asm volatile("s_waitcnt vmcnt(2) lgkmcnt(0)" ::: "memory");
        __builtin_amdgcn_s_barrier();   // all waves: tile it resident

        const unsigned short* Ks = (const unsigned short*)(SH + b0);
        const unsigned short* Vs = (const unsigned short*)(SH + b0 + 8192);

        // fragment ds_reads for tile it, issued up front
        bf16x8 kfc[4];
        #pragma unroll
        for (int s = 0; s < 4; ++s) kfc[s] = *(const bf16x8*)&Ks[kOffL[s]];
        bf16x8 vfc[2][2];
        #pragma unroll
        for (int dt = 0; dt < 2; ++dt)
            #pragma unroll
            for (int ks = 0; ks < 2; ++ks)
                vfc[dt][ks] = *(const bf16x8*)&Vs[vOffL[dt][ks]];

        // K(it+1) f32 register loads (auto-vmcnt before the cvt below)
        if (it + 1 < NIT) {
            const size_t kv = (size_t)(it + 1) * TK;
            ka0 = *(const float4*)&KhF[kv * HD + kG0];
            ka1 = *(const float4*)&KhF[kv * HD + kG0 + 4];
            kb0 = *(const float4*)&KhF[kv * HD + kG1];
            kb1 = *(const float4*)&KhF[kv * HD + kG1 + 4];
        }
        // V(it+2) async cp into rotating buffer's V-half
        if (it + 2 < NIT) {
            const size_t kv = (size_t)(it + 2) * TK;
            unsigned short* Vn = (unsigned short*)(SH + b2 + 8192);
            async_cp16(Vh + kv + vG0, &Vn[dst0]);
            async_cp16(Vh + kv + vG1, &Vn[dst1]);
        }

        // FIN(it-1): register-only, fills the ds_read/global-load shadow
        FIN(scp, vfp);

        // QK MFMAs for tile it
        f32x16 scc = (f32x16)(0.f);
        __builtin_amdgcn_s_setprio(1);
        #pragma unroll
        for (int s = 0; s < 4; ++s)
            scc = __builtin_amdgcn_mfma_f32_32x32x16_bf16(kfc[s], qf[s], scc, 0, 0, 0);
        __builtin_amdgcn_s_setprio(0);

        // K(it+1): cvt + ds_write into buf (it+1)%3 K-half
        if (it + 1 < NIT)
            stageK(ka0, ka1, kb0, kb1, (unsigned short*)(SH + b1));

        scp = scc;
        #pragma unroll
        for (int dt = 0; dt < 2; ++dt)
            #pragma unroll
            for (int ks = 0; ks < 2; ++ks)
                vfp[dt][ks] = vfc[dt][ks];

        unsigned int btmp = b0; b0 = b1; b1 = b2; b2 = btmp;
    }

    // ---- tail: finish the last tile ----
    FIN(scp, vfp);

    // ---- epilogue: combine nt partials (O and lsum), normalize, store ----
    // ORed overlays buf0; tile 31 lives in buf 31%3=1; every wave's buf0 reads
    // completed before barrier(31), so writing ORed here cannot race them.
    lsum += __shfl_xor(lsum, 32, 64);

    if (nt == 1) {
        if (lane < 32) Lsum[mt * 32 + lane] = lsum;
        #pragma unroll
        for (int dt = 0; dt < 2; ++dt) {
            const int d = dt * 32 + l31;
            #pragma unroll
            for (int g = 0; g < 4; ++g) {
                const int m0 = mt * 32 + 8 * g + 4 * hi;
                const int ph = (m0 >> 2) ^ (d & 15);
                float4 v = { o[dt][4*g+0], o[dt][4*g+1], o[dt][4*g+2], o[dt][4*g+3] };
                *(float4*)&ORed[d * 64 + ph * 4] = v;
            }
        }
    }
    __syncthreads();

    if (nt == 0) {
        float ltot = lsum + Lsum[mt * 32 + l31];
        if (lane < 32) Linv[mt * 32 + lane] = 1.0f / ltot;
        float* Oh = O + ((size_t)bh * SEQ + q0) * HD;
        #pragma unroll
        for (int dt = 0; dt < 2; ++dt) {
            const int d = dt * 32 + l31;
            #pragma unroll
            for (int g = 0; g < 4; ++g) {
                const int m0 = mt * 32 + 8 * g + 4 * hi;
                const int ph = (m0 >> 2) ^ (d & 15);
                float4 part = *(const float4*)&ORed[d * 64 + ph * 4];
                float4 inv4 = *(const float4*)&Linv[m0];
                const float* pp = (const float*)&part;
                const float* ii = (const float*)&inv4;
                #pragma unroll
                for (int j = 0; j < 4; ++j)
                    Oh[(size_t)(m0 + j) * HD + d] = (o[dt][4*g+j] + pp[j]) * ii[j];
            }
        }
    }
}

// ---------------- fallback (no-workspace) kernel ----------------
#define PAD 8
#define LSTR (HD + PAD)

__global__ __launch_bounds__(256)
void fa_fwd_fb(const float* __restrict__ Q, const float* __restrict__ K,
               const float* __restrict__ V, float* __restrict__ O) {
    const int x  = blockIdx.x & 7;
    const int t  = blockIdx.x >> 3;
    const int bh = x + 8 * (t % 3);
    const int qt = t / 3;
    const int q0 = qt * TQ;
    const long base = (long)bh * SEQ * HD;

    __shared__ unsigned short Qs[TQ][LSTR];
    __shared__ unsigned short Ks2[64][LSTR];
    __shared__ unsigned short Vt[HD][64 + PAD];
    __shared__ unsigned short Ps2[4][16][LSTR];

    const int tid  = threadIdx.x;
    const int wave = tid >> 6;
    const int lane = tid & 63;
    const int col  = lane & 15;
    const int quad = lane >> 4;
    const int m0   = wave * 16;

    #pragma unroll
    for (int i = 0; i < 4; ++i) {
        int idx = tid + 256 * i;
        int row = idx >> 4;
        int c4  = (idx & 15) * 4;
        float4 v = *(const float4*)&Q[base + (long)(q0 + row) * HD + c4];
        ushort4 b = { f2bf(v.x), f2bf(v.y), f2bf(v.z), f2bf(v.w) };
        *(ushort4*)&Qs[row][c4] = b;
    }
    __syncthreads();

    bf16x8 aq0 = *(const bf16x8*)&Qs[m0 + col][quad * 8];
    bf16x8 aq1 = *(const bf16x8*)&Qs[m0 + col][32 + quad * 8];

    f32x4 o0 = {0.f,0.f,0.f,0.f}, o1 = o0, o2 = o0, o3 = o0;
    float l[4] = {0.f, 0.f, 0.f, 0.f};
    const float scale = 0.022097086912079608f;

    for (int kv0 = 0; kv0 < SEQ; kv0 += 64) {
        __syncthreads();
        #pragma unroll
        for (int i = 0; i < 4; ++i) {
            int idx = tid + 256 * i;
            int row = idx >> 4;
            int c4  = (idx & 15) * 4;
            float4 kv = *(const float4*)&K[base + (long)(kv0 + row) * HD + c4];
            ushort4 kb = { f2bf(kv.x), f2bf(kv.y), f2bf(kv.z), f2bf(kv.w) };
            *(ushort4*)&Ks2[row][c4] = kb;
            float4 vv = *(const float4*)&V[base + (long)(kv0 + row) * HD + c4];
            Vt[c4 + 0][row] = f2bf(vv.x);
            Vt[c4 + 1][row] = f2bf(vv.y);
            Vt[c4 + 2][row] = f2bf(vv.z);
            Vt[c4 + 3][row] = f2bf(vv.w);
        }
        __syncthreads();

        f32x4 sc[4];
        #pragma unroll
        for (int n = 0; n < 4; ++n) {
            bf16x8 b0 = *(const bf16x8*)&Ks2[n * 16 + col][quad * 8];
            bf16x8 b1 = *(const bf16x8*)&Ks2[n * 16 + col][32 + quad * 8];
            f32x4 acc = {0.f,0.f,0.f,0.f};
            acc = __builtin_amdgcn_mfma_f32_16x16x32_bf16(aq0, b0, acc, 0, 0, 0);
            acc = __builtin_amdgcn_mfma_f32_16x16x32_bf16(aq1, b1, acc, 0, 0, 0);
            sc[n] = acc;
        }

        float tsum[4] = {0.f, 0.f, 0.f, 0.f};
        #pragma unroll
        for (int n = 0; n < 4; ++n) {
            #pragma unroll
            for (int r = 0; r < 4; ++r) {
                float p = __expf(sc[n][r] * scale);
                tsum[r] += p;
                Ps2[wave][quad * 4 + r][n * 16 + col] = f2bf(p);
            }
        }
        #pragma unroll
        for (int off = 1; off < 16; off <<= 1) {
            #pragma unroll
            for (int r = 0; r < 4; ++r) tsum[r] += __shfl_xor(tsum[r], off, 64);
        }
        #pragma unroll
        for (int r = 0; r < 4; ++r) l[r] += tsum[r];

        bf16x8 ap0 = *(const bf16x8*)&Ps2[wave][col][quad * 8];
        bf16x8 ap1 = *(const bf16x8*)&Ps2[wave][col][32 + quad * 8];
        #pragma unroll
        for (int n = 0; n < 4; ++n) {
            bf16x8 b0 = *(const bf16x8*)&Vt[n * 16 + col][quad * 8];
            bf16x8 b1 = *(const bf16x8*)&Vt[n * 16 + col][32 + quad * 8];
            f32x4* op = (n == 0) ? &o0 : (n == 1) ? &o1 : (n == 2) ? &o2 : &o3;
            *op = __builtin_amdgcn_mfma_f32_16x16x32_bf16(ap0, b0, *op, 0, 0, 0);
            *op = __builtin_amdgcn_mfma_f32_16x16x32_bf16(ap1, b1, *op, 0, 0, 0);
        }
    }

    float inv[4];
    #pragma unroll
    for (int r = 0; r < 4; ++r) inv[r] = 1.0f / l[r];
    #pragma unroll
    for (int r = 0; r < 4; ++r) {
        long row = base + (long)(q0 + m0 + quad * 4 + r) * HD;
        O[row +  0 + col] = o0[r] * inv[r];
        O[row + 16 + col] = o1[r] * inv[r];
        O[row + 32 + col] = o2[r] * inv[r];
        O[row + 48 + col] = o3[r] * inv[r];
    }
}

extern "C" void kernel_launch(void* const* d_in, const int* in_sizes, int n_in,
                              void* d_out, int out_size, void* d_ws, size_t ws_size,
                              hipStream_t stream) {
    const float* Q = (const float*)d_in[0];
    const float* K = (const float*)d_in[1];
    const float* V = (const float*)d_in[2];
    float* O = (float*)d_out;

    const size_t tensorElems = (size_t)NHEADS * SEQ * HD;
    const size_t need = tensorElems * sizeof(unsigned short);   // Vtb only

    if (ws_size >= need) {
        unsigned short* Vtb = (unsigned short*)d_ws;
        const float qs = (float)(1.4426950408889634 / sqrt(2048.0));  // log2e/sqrt(S)
        prep_v<<<dim3(NHEADS * (SEQ / 64)), dim3(256), 0, stream>>>(V, Vtb);
        fa_main<<<dim3(NHEADS * (SEQ / TQ)), dim3(256), 0, stream>>>(Q, K, Vtb, O, qs);
    } else {
        fa_fwd_fb<<<dim3(NHEADS * (SEQ / TQ)), dim3(256), 0, stream>>>(Q, K, V, O);
    }
}

// Round 9
// 115.620 us; speedup vs baseline: 1.0540x; 1.0540x over previous
//
#include <hip/hip_runtime.h>
#include <hip/hip_bf16.h>
#include <math.h>
#include <stdint.h>

#define BATCH 2
#define NH 12
#define SEQ 2048
#define HD 64
#define TQ 64
#define TK 64
#define NHEADS (BATCH*NH)
#define NIT (SEQ / TK)

typedef short bf16x8 __attribute__((ext_vector_type(8)));
typedef float f32x4 __attribute__((ext_vector_type(4)));
typedef float f32x16 __attribute__((ext_vector_type(16)));
typedef unsigned short us4_t __attribute__((ext_vector_type(4)));
typedef unsigned short us8_t __attribute__((ext_vector_type(8)));
typedef unsigned int u32x4 __attribute__((ext_vector_type(4)));

#if __has_builtin(__builtin_amdgcn_exp2f)
#define EXP2F(x) __builtin_amdgcn_exp2f(x)
#else
#define EXP2F(x) exp2f(x)
#endif

static __device__ __forceinline__ unsigned short f2bf(float f) {
    unsigned int u = __float_as_uint(f);
    u += 0x7fffu + ((u >> 16) & 1u);   // RTNE
    return (unsigned short)(u >> 16);
}

static __device__ __forceinline__ unsigned int pack2bf(float a, float b) {
    __hip_bfloat162 v = __float22bfloat162_rn(float2{a, b});
    return *(unsigned int*)&v;          // low short = a
}

// Conflict-free 64x64-bf16 tile layout (staging only): 32 row-pairs x 256B,
// 16 positions of 16B, pos = ((r&1)*8 | c) ^ ((r>>1)&15).
static __device__ __forceinline__ int tile_off(int r, int c) {   // shorts, c 0..7
    int rp  = r >> 1;
    int pos = (((r & 1) << 3) | c) ^ (rp & 15);
    return rp * 128 + pos * 8;
}

// ---- pre-pass (R15): K and V -> FRAGMENT-LINEAR bf16 workspaces.
// Kb:  per (bh,tile,nt): 2048 shorts = [s 0..3][lane 0..63] of 8 bf16 each,
//      frag(s,lane) = K_bf16[nt*32 + (lane&31)][(s*2 + (lane>>5))*8 .. +8].
// Vtb: per (bh,tile): 4096 shorts = [(nt*2+ks) 0..3][hi 0..1][row 0..63],
//      frag = V^T[row][( (nt*4+ks*2+hi)*8 .. +8 ) pi-permuted s].
// Every fa_main load becomes base + lane*16B -> fully coalesced.
__global__ __launch_bounds__(256)
void prep_kv(const float* __restrict__ K, const float* __restrict__ V,
             unsigned short* __restrict__ Kb, unsigned short* __restrict__ Vtb) {
    __shared__ unsigned short T[64][66];       // V transpose staging
    __shared__ unsigned short KT[4096];        // K tile in tile_off layout (8 KB)
    const int bh   = blockIdx.x >> 5;
    const int tile = blockIdx.x & 31;
    const int s0   = tile * 64;
    const int tid  = threadIdx.x;
    const size_t off = ((size_t)bh * SEQ + s0) * HD;

    #pragma unroll
    for (int u = 0; u < 4; ++u) {              // K: dense f32 -> KT (tile_off)
        int idx = u * 1024 + tid * 4;
        int r = idx >> 6, col = idx & 63;
        float4 a = *(const float4*)&K[off + idx];
        uint2 pk = { pack2bf(a.x, a.y), pack2bf(a.z, a.w) };
        *(uint2*)&KT[tile_off(r, col >> 3) + (col & 7)] = pk;
    }
    #pragma unroll
    for (int u = 0; u < 4; ++u) {              // V: dense loads -> padded LDS
        int idx = u * 1024 + tid * 4;
        int r = idx >> 6, col = idx & 63;
        float4 a = *(const float4*)&V[off + idx];
        *(unsigned int*)&T[r][col]     = pack2bf(a.x, a.y);
        *(unsigned int*)&T[r][col + 2] = pack2bf(a.z, a.w);
    }
    __syncthreads();

    // K fragment writes: 256 threads = 64 lanes x 4 s; loop nt. 16B/lane,
    // lane-consecutive -> 1KB contiguous per wave-store.
    {
        const int lane = tid & 63, s = tid >> 6;
        unsigned short* KbT = Kb + ((size_t)(bh * 32 + tile) * 2) * 2048;
        #pragma unroll
        for (int nt = 0; nt < 2; ++nt) {
            bf16x8 f = *(const bf16x8*)&KT[tile_off(nt * 32 + (lane & 31),
                                                    s * 2 + (lane >> 5))];
            *(bf16x8*)&KbT[(size_t)nt * 2048 + s * 512 + lane * 8] = f;
        }
    }
    // V fragment writes (pi-permuted gather from T, as before; new dst addr)
    {
        unsigned short* VbT = Vtb + (size_t)(bh * 32 + tile) * 4096;
        const int g = tid & 7, dd = tid >> 3;  // dd 0..31
        const int cg = ((g >> 2) * 2 + ((g >> 1) & 1));   // (nt*2+ks)
        const int hi = g & 1;
        #pragma unroll
        for (int h = 0; h < 2; ++h) {
            int d = dd + 32 * h;               // V^T row = d-index
            us8_t r8;
            #pragma unroll
            for (int j = 0; j < 8; ++j) {
                // pi: swap bits 2,3 of the 64-local column index (g*8 + j)
                int src = ((g >> 1) << 4) + ((j >> 2) << 3) + ((g & 1) << 2) + (j & 3);
                r8[j] = T[src][d];
            }
            *(us8_t*)&VbT[(size_t)cg * 1024 + hi * 512 + d * 8] = r8;
        }
    }
}

// ---------------- main flash-attention kernel (32x32x16 MFMA) ----------------
// R15: BARRIER-FREE main loop. R11 failed because row-major global fragments
// shattered into 32 transactions/load; the fragment-linear workspace makes
// every load base+lane*16 (1-2 contiguous transactions). So: no LDS, no
// s_barrier, no waitcnt asm in the loop — waves run independently (m191
// setprio-positive regime); compiler inserts exact vmcnt waits.
// Pipeline per iter t: issue V(t)+K(t) loads -> FIN(t-1) (register-only,
// covers K's load latency) -> QK(t) -> rotate {scp, vfp}. V has 1-iter cover,
// K is covered by FIN (~500cyc vs ~300cyc L2-hot). mt-paired waves read
// identical fragments -> L1 hit. Fragment contents bit-identical to the old
// LDS reads -> absmax unchanged. LDS only for Q staging + epilogue (16.9KB).
__global__ __launch_bounds__(256, 3)
void fa_main(const float* __restrict__ Q,
             const unsigned short* __restrict__ Kb,
             const unsigned short* __restrict__ Vtb,
             float* __restrict__ O, float qs) {
    const int x  = blockIdx.x & 7;
    const int t  = blockIdx.x >> 3;
    const int bh = x + 8 * (t % 3);
    const int qt = t / 3;
    const int q0 = qt * TQ;

    __shared__ __align__(16) unsigned char SH[16896];
    unsigned short* QS = (unsigned short*)SH;              // prologue only
    float* ORed = (float*)SH;                              // 64x64 f32 (epilogue)
    float* Lsum = (float*)(SH + 16384);                    // 64 f32
    float* Linv = (float*)(SH + 16640);                    // 64 f32

    const int tid  = threadIdx.x;
    const int w    = tid >> 6;
    const int mt   = w >> 1;
    const int nt   = w & 1;
    const int lane = tid & 63;
    const int l31  = lane & 31;
    const int hi   = lane >> 5;

    const float* Qh = Q + ((size_t)bh * SEQ + q0) * HD;

    // ---- prologue: Q (fp32 -> scaled bf16) -> QS; extract B-fragments ----
    #pragma unroll
    for (int u = 0; u < 4; ++u) {
        int idx = u * 1024 + tid * 4;
        int r = idx >> 6, col = idx & 63;
        float4 a = *(const float4*)&Qh[idx];
        uint2 pk = { pack2bf(a.x * qs, a.y * qs), pack2bf(a.z * qs, a.w * qs) };
        *(uint2*)&QS[tile_off(r, col >> 3) + (col & 7)] = pk;
    }
    __syncthreads();
    bf16x8 qf[4];
    #pragma unroll
    for (int s = 0; s < 4; ++s)
        qf[s] = *(const bf16x8*)&QS[tile_off(mt * 32 + l31, s * 2 + hi)];
    __syncthreads();   // all waves extracted qf; ORed overlay safe after this

    // ---- per-lane fragment-linear bases (advance 4096 shorts per tile) ----
    const unsigned short* kB = Kb  + ((size_t)bh * 32 * 2 + nt) * 2048 + lane * 8;
    const unsigned short* vB = Vtb + (size_t)bh * 32 * 4096
                                   + (size_t)(nt * 2) * 1024 + hi * 512 + l31 * 8;

    f32x16 o[2];
    o[0] = (f32x16)(0.f);
    o[1] = (f32x16)(0.f);
    float lsum = 0.f;

    // deferred finish: exp2 + pack + PV + lsum (register-only)
    auto FIN = [&](const f32x16& sp, const bf16x8 (&vp)[2][2]) {
        float e0[8], e1[8];
        #pragma unroll
        for (int r = 0; r < 8; ++r) e0[r] = EXP2F(sp[r]);
        #pragma unroll
        for (int r = 0; r < 8; ++r) e1[r] = EXP2F(sp[8 + r]);
        union { u32x4 d; bf16x8 h; } pu0, pu1;
        pu0.d = (u32x4){ pack2bf(e0[0], e0[1]), pack2bf(e0[2], e0[3]),
                         pack2bf(e0[4], e0[5]), pack2bf(e0[6], e0[7]) };
        pu1.d = (u32x4){ pack2bf(e1[0], e1[1]), pack2bf(e1[2], e1[3]),
                         pack2bf(e1[4], e1[5]), pack2bf(e1[6], e1[7]) };
        bf16x8 pf0 = pu0.h, pf1 = pu1.h;
        __builtin_amdgcn_s_setprio(1);
        o[0] = __builtin_amdgcn_mfma_f32_32x32x16_bf16(pf0, vp[0][0], o[0], 0, 0, 0);
        o[1] = __builtin_amdgcn_mfma_f32_32x32x16_bf16(pf0, vp[1][0], o[1], 0, 0, 0);
        o[0] = __builtin_amdgcn_mfma_f32_32x32x16_bf16(pf1, vp[0][1], o[0], 0, 0, 0);
        o[1] = __builtin_amdgcn_mfma_f32_32x32x16_bf16(pf1, vp[1][1], o[1], 0, 0, 0);
        __builtin_amdgcn_s_setprio(0);
        float t0 = ((e0[0] + e0[1]) + (e0[2] + e0[3]))
                 + ((e0[4] + e0[5]) + (e0[6] + e0[7]));
        float t1 = ((e1[0] + e1[1]) + (e1[2] + e1[3]))
                 + ((e1[4] + e1[5]) + (e1[6] + e1[7]));
        lsum += t0 + t1;
    };

    // pipeline state
    f32x16 scp;
    bf16x8 vfp[2][2];

    // ---- peeled iteration 0 ----
    {
        bf16x8 kc[4];
        #pragma unroll
        for (int s = 0; s < 4; ++s) kc[s] = *(const bf16x8*)(kB + s * 512);
        #pragma unroll
        for (int dt = 0; dt < 2; ++dt)
            #pragma unroll
            for (int ks = 0; ks < 2; ++ks)
                vfp[dt][ks] = *(const bf16x8*)(vB + ks * 1024 + dt * 256);
        f32x16 sc = (f32x16)(0.f);
        __builtin_amdgcn_s_setprio(1);
        #pragma unroll
        for (int s = 0; s < 4; ++s)
            sc = __builtin_amdgcn_mfma_f32_32x32x16_bf16(kc[s], qf[s], sc, 0, 0, 0);
        __builtin_amdgcn_s_setprio(0);
        scp = sc;
    }

    // ---- main loop (no barriers): iter t = {load V(t),K(t) -> FIN(t-1) ->
    //                                          QK(t) -> rotate} ----
    #pragma unroll 2
    for (int it = 1; it < NIT; ++it) {
        const unsigned short* kT = kB + (size_t)it * 4096;
        const unsigned short* vT = vB + (size_t)it * 4096;

        // V(t) for next FIN (1-iter cover); K(t) for this iter's QK (FIN cover)
        bf16x8 vn[2][2];
        #pragma unroll
        for (int dt = 0; dt < 2; ++dt)
            #pragma unroll
            for (int ks = 0; ks < 2; ++ks)
                vn[dt][ks] = *(const bf16x8*)(vT + ks * 1024 + dt * 256);
        bf16x8 kc[4];
        #pragma unroll
        for (int s = 0; s < 4; ++s) kc[s] = *(const bf16x8*)(kT + s * 512);

        // FIN(t-1): register-only, fills K/V load shadow
        FIN(scp, vfp);

        // QK(t)
        f32x16 scc = (f32x16)(0.f);
        __builtin_amdgcn_s_setprio(1);
        #pragma unroll
        for (int s = 0; s < 4; ++s)
            scc = __builtin_amdgcn_mfma_f32_32x32x16_bf16(kc[s], qf[s], scc, 0, 0, 0);
        __builtin_amdgcn_s_setprio(0);

        scp = scc;
        #pragma unroll
        for (int dt = 0; dt < 2; ++dt)
            #pragma unroll
            for (int ks = 0; ks < 2; ++ks)
                vfp[dt][ks] = vn[dt][ks];
    }

    // ---- tail: finish the last tile ----
    FIN(scp, vfp);

    // ---- epilogue: combine nt partials (O and lsum), normalize, store ----
    lsum += __shfl_xor(lsum, 32, 64);

    if (nt == 1) {
        if (lane < 32) Lsum[mt * 32 + lane] = lsum;
        #pragma unroll
        for (int dt = 0; dt < 2; ++dt) {
            const int d = dt * 32 + l31;
            #pragma unroll
            for (int g = 0; g < 4; ++g) {
                const int m0 = mt * 32 + 8 * g + 4 * hi;
                const int ph = (m0 >> 2) ^ (d & 15);
                float4 v = { o[dt][4*g+0], o[dt][4*g+1], o[dt][4*g+2], o[dt][4*g+3] };
                *(float4*)&ORed[d * 64 + ph * 4] = v;
            }
        }
    }
    __syncthreads();

    if (nt == 0) {
        float ltot = lsum + Lsum[mt * 32 + l31];
        if (lane < 32) Linv[mt * 32 + lane] = 1.0f / ltot;
        float* Oh = O + ((size_t)bh * SEQ + q0) * HD;
        #pragma unroll
        for (int dt = 0; dt < 2; ++dt) {
            const int d = dt * 32 + l31;
            #pragma unroll
            for (int g = 0; g < 4; ++g) {
                const int m0 = mt * 32 + 8 * g + 4 * hi;
                const int ph = (m0 >> 2) ^ (d & 15);
                float4 part = *(const float4*)&ORed[d * 64 + ph * 4];
                float4 inv4 = *(const float4*)&Linv[m0];
                const float* pp = (const float*)&part;
                const float* ii = (const float*)&inv4;
                #pragma unroll
                for (int j = 0; j < 4; ++j)
                    Oh[(size_t)(m0 + j) * HD + d] = (o[dt][4*g+j] + pp[j]) * ii[j];
            }
        }
    }
}

// ---------------- fallback (no-workspace) kernel ----------------
#define PAD 8
#define LSTR (HD + PAD)

__global__ __launch_bounds__(256)
void fa_fwd_fb(const float* __restrict__ Q, const float* __restrict__ K,
               const float* __restrict__ V, float* __restrict__ O) {
    const int x  = blockIdx.x & 7;
    const int t  = blockIdx.x >> 3;
    const int bh = x + 8 * (t % 3);
    const int qt = t / 3;
    const int q0 = qt * TQ;
    const long base = (long)bh * SEQ * HD;

    __shared__ unsigned short Qs[TQ][LSTR];
    __shared__ unsigned short Ks2[64][LSTR];
    __shared__ unsigned short Vt[HD][64 + PAD];
    __shared__ unsigned short Ps2[4][16][LSTR];

    const int tid  = threadIdx.x;
    const int wave = tid >> 6;
    const int lane = tid & 63;
    const int col  = lane & 15;
    const int quad = lane >> 4;
    const int m0   = wave * 16;

    #pragma unroll
    for (int i = 0; i < 4; ++i) {
        int idx = tid + 256 * i;
        int row = idx >> 4;
        int c4  = (idx & 15) * 4;
        float4 v = *(const float4*)&Q[base + (long)(q0 + row) * HD + c4];
        ushort4 b = { f2bf(v.x), f2bf(v.y), f2bf(v.z), f2bf(v.w) };
        *(ushort4*)&Qs[row][c4] = b;
    }
    __syncthreads();

    bf16x8 aq0 = *(const bf16x8*)&Qs[m0 + col][quad * 8];
    bf16x8 aq1 = *(const bf16x8*)&Qs[m0 + col][32 + quad * 8];

    f32x4 o0 = {0.f,0.f,0.f,0.f}, o1 = o0, o2 = o0, o3 = o0;
    float l[4] = {0.f, 0.f, 0.f, 0.f};
    const float scale = 0.022097086912079608f;

    for (int kv0 = 0; kv0 < SEQ; kv0 += 64) {
        __syncthreads();
        #pragma unroll
        for (int i = 0; i < 4; ++i) {
            int idx = tid + 256 * i;
            int row = idx >> 4;
            int c4  = (idx & 15) * 4;
            float4 kv = *(const float4*)&K[base + (long)(kv0 + row) * HD + c4];
            ushort4 kb = { f2bf(kv.x), f2bf(kv.y), f2bf(kv.z), f2bf(kv.w) };
            *(ushort4*)&Ks2[row][c4] = kb;
            float4 vv = *(const float4*)&V[base + (long)(kv0 + row) * HD + c4];
            Vt[c4 + 0][row] = f2bf(vv.x);
            Vt[c4 + 1][row] = f2bf(vv.y);
            Vt[c4 + 2][row] = f2bf(vv.z);
            Vt[c4 + 3][row] = f2bf(vv.w);
        }
        __syncthreads();

        f32x4 sc[4];
        #pragma unroll
        for (int n = 0; n < 4; ++n) {
            bf16x8 b0 = *(const bf16x8*)&Ks2[n * 16 + col][quad * 8];
            bf16x8 b1 = *(const bf16x8*)&Ks2[n * 16 + col][32 + quad * 8];
            f32x4 acc = {0.f,0.f,0.f,0.f};
            acc = __builtin_amdgcn_mfma_f32_16x16x32_bf16(aq0, b0, acc, 0, 0, 0);
            acc = __builtin_amdgcn_mfma_f32_16x16x32_bf16(aq1, b1, acc, 0, 0, 0);
            sc[n] = acc;
        }

        float tsum[4] = {0.f, 0.f, 0.f, 0.f};
        #pragma unroll
        for (int n = 0; n < 4; ++n) {
            #pragma unroll
            for (int r = 0; r < 4; ++r) {
                float p = __expf(sc[n][r] * scale);
                tsum[r] += p;
                Ps2[wave][quad * 4 + r][n * 16 + col] = f2bf(p);
            }
        }
        #pragma unroll
        for (int off = 1; off < 16; off <<= 1) {
            #pragma unroll
            for (int r = 0; r < 4; ++r) tsum[r] += __shfl_xor(tsum[r], off, 64);
        }
        #pragma unroll
        for (int r = 0; r < 4; ++r) l[r] += tsum[r];

        bf16x8 ap0 = *(const bf16x8*)&Ps2[wave][col][quad * 8];
        bf16x8 ap1 = *(const bf16x8*)&Ps2[wave][col][32 + quad * 8];
        #pragma unroll
        for (int n = 0; n < 4; ++n) {
            bf16x8 b0 = *(const bf16x8*)&Vt[n * 16 + col][quad * 8];
            bf16x8 b1 = *(const bf16x8*)&Vt[n * 16 + col][32 + quad * 8];
            f32x4* op = (n == 0) ? &o0 : (n == 1) ? &o1 : (n == 2) ? &o2 : &o3;
            *op = __builtin_amdgcn_mfma_f32_16x16x32_bf16(ap0, b0, *op, 0, 0, 0);
            *op = __builtin_amdgcn_mfma_f32_16x16x32_bf16(ap1, b1, *op, 0, 0, 0);
        }
    }

    float inv[4];
    #pragma unroll
    for (int r = 0; r < 4; ++r) inv[r] = 1.0f / l[r];
    #pragma unroll
    for (int r = 0; r < 4; ++r) {
        long row = base + (long)(q0 + m0 + quad * 4 + r) * HD;
        O[row +  0 + col] = o0[r] * inv[r];
        O[row + 16 + col] = o1[r] * inv[r];
        O[row + 32 + col] = o2[r] * inv[r];
        O[row + 48 + col] = o3[r] * inv[r];
    }
}

extern "C" void kernel_launch(void* const* d_in, const int* in_sizes, int n_in,
                              void* d_out, int out_size, void* d_ws, size_t ws_size,
                              hipStream_t stream) {
    const float* Q = (const float*)d_in[0];
    const float* K = (const float*)d_in[1];
    const float* V = (const float*)d_in[2];
    float* O = (float*)d_out;

    const size_t tensorElems = (size_t)NHEADS * SEQ * HD;
    const size_t need = 2 * tensorElems * sizeof(unsigned short);

    if (ws_size >= need) {
        unsigned short* Kb  = (unsigned short*)d_ws;
        unsigned short* Vtb = Kb + tensorElems;
        const float qs = (float)(1.4426950408889634 / sqrt(2048.0));  // log2e/sqrt(S)
        prep_kv<<<dim3(NHEADS * (SEQ / 64)), dim3(256), 0, stream>>>(K, V, Kb, Vtb);
        fa_main<<<dim3(NHEADS * (SEQ / TQ)), dim3(256), 0, stream>>>(Q, Kb, Vtb, O, qs);
    } else {
        fa_fwd_fb<<<dim3(NHEADS * (SEQ / TQ)), dim3(256), 0, stream>>>(Q, K, V, O);
    }
}

// Round 10
// 115.156 us; speedup vs baseline: 1.0582x; 1.0040x over previous
//
#include <hip/hip_runtime.h>
#include <hip/hip_bf16.h>
#include <math.h>
#include <stdint.h>

#define BATCH 2
#define NH 12
#define SEQ 2048
#define HD 64
#define TQ 64
#define TK 64
#define NHEADS (BATCH*NH)
#define NIT (SEQ / TK)

typedef short bf16x8 __attribute__((ext_vector_type(8)));
typedef float f32x4 __attribute__((ext_vector_type(4)));
typedef float f32x16 __attribute__((ext_vector_type(16)));
typedef unsigned short us4_t __attribute__((ext_vector_type(4)));
typedef unsigned short us8_t __attribute__((ext_vector_type(8)));
typedef unsigned int u32x4 __attribute__((ext_vector_type(4)));

#if __has_builtin(__builtin_amdgcn_exp2f)
#define EXP2F(x) __builtin_amdgcn_exp2f(x)
#else
#define EXP2F(x) exp2f(x)
#endif

static __device__ __forceinline__ unsigned short f2bf(float f) {
    unsigned int u = __float_as_uint(f);
    u += 0x7fffu + ((u >> 16) & 1u);   // RTNE
    return (unsigned short)(u >> 16);
}

static __device__ __forceinline__ unsigned int pack2bf(float a, float b) {
    __hip_bfloat162 v = __float22bfloat162_rn(float2{a, b});
    return *(unsigned int*)&v;          // low short = a
}

// Conflict-free 64x64-bf16 tile layout (staging only): 32 row-pairs x 256B,
// 16 positions of 16B, pos = ((r&1)*8 | c) ^ ((r>>1)&15).
static __device__ __forceinline__ int tile_off(int r, int c) {   // shorts, c 0..7
    int rp  = r >> 1;
    int pos = (((r & 1) << 3) | c) ^ (rp & 15);
    return rp * 128 + pos * 8;
}

// ---- pre-pass (R16): K and V -> FRAGMENT-LINEAR bf16 workspaces.
// Kb:  per (bh,tile,nt): 2048 shorts = [s 0..3][lane 0..63] of 8 bf16 each.
// Vtb: per (bh,tile): 4096 shorts, fragment index o8 = cg*128 + hi*64 + d.
// R16 fix vs R15: V fragment writes are now TID-LINEAR (consecutive tids write
// consecutive 16B -> dense 4KB per pass, vs R15's 64x16B scatter per wave).
// Bonus: all lanes of a wave share g, so the T gather reads one contiguous
// 128B row per j (conflict-free broadcast row-read).
__global__ __launch_bounds__(256)
void prep_kv(const float* __restrict__ K, const float* __restrict__ V,
             unsigned short* __restrict__ Kb, unsigned short* __restrict__ Vtb) {
    __shared__ unsigned short T[64][66];       // V transpose staging
    __shared__ unsigned short KT[4096];        // K tile in tile_off layout (8 KB)
    const int bh   = blockIdx.x >> 5;
    const int tile = blockIdx.x & 31;
    const int s0   = tile * 64;
    const int tid  = threadIdx.x;
    const size_t off = ((size_t)bh * SEQ + s0) * HD;

    #pragma unroll
    for (int u = 0; u < 4; ++u) {              // K: dense f32 -> KT (tile_off)
        int idx = u * 1024 + tid * 4;
        int r = idx >> 6, col = idx & 63;
        float4 a = *(const float4*)&K[off + idx];
        uint2 pk = { pack2bf(a.x, a.y), pack2bf(a.z, a.w) };
        *(uint2*)&KT[tile_off(r, col >> 3) + (col & 7)] = pk;
    }
    #pragma unroll
    for (int u = 0; u < 4; ++u) {              // V: dense loads -> padded LDS
        int idx = u * 1024 + tid * 4;
        int r = idx >> 6, col = idx & 63;
        float4 a = *(const float4*)&V[off + idx];
        *(unsigned int*)&T[r][col]     = pack2bf(a.x, a.y);
        *(unsigned int*)&T[r][col + 2] = pack2bf(a.z, a.w);
    }
    __syncthreads();

    // K fragment writes: 256 threads = 64 lanes x 4 s; loop nt. 16B/lane,
    // lane-consecutive -> 1KB contiguous per wave-store.
    {
        const int lane = tid & 63, s = tid >> 6;
        unsigned short* KbT = Kb + ((size_t)(bh * 32 + tile) * 2) * 2048;
        #pragma unroll
        for (int nt = 0; nt < 2; ++nt) {
            bf16x8 f = *(const bf16x8*)&KT[tile_off(nt * 32 + (lane & 31),
                                                    s * 2 + (lane >> 5))];
            *(bf16x8*)&KbT[(size_t)nt * 2048 + s * 512 + lane * 8] = f;
        }
    }
    // V fragment writes: tid-linear fragment index -> dense contiguous stores.
    {
        unsigned short* VbT = Vtb + (size_t)(bh * 32 + tile) * 4096;
        #pragma unroll
        for (int h = 0; h < 2; ++h) {
            int o8 = tid + 256 * h;            // fragment index 0..511
            int d  = o8 & 63;                  // V^T row (d-index)
            int hi = (o8 >> 6) & 1;
            int cg = o8 >> 7;                  // (nt*2+ks), 0..3
            int g  = ((cg >> 1) << 2) | ((cg & 1) << 1) | hi;
            us8_t r8;
            #pragma unroll
            for (int j = 0; j < 8; ++j) {
                // pi: swap bits 2,3 of the 64-local column index (g*8 + j)
                int src = ((g >> 1) << 4) + ((j >> 2) << 3) + ((g & 1) << 2) + (j & 3);
                r8[j] = T[src][d];
            }
            *(us8_t*)&VbT[o8 * 8] = r8;
        }
    }
}

// ---------------- main flash-attention kernel (32x32x16 MFMA) ----------------
// R16 = R15 (barrier-free main loop over fragment-linear K/V; no LDS, no
// s_barrier, no waitcnt asm in the loop; deferred-PV FIN) with K fragments
// software-pipelined at distance 1 (symmetric with V): iter t issues
// K(t+1)+V(t) loads; FIN(t-1) and QK(t) consume registers loaded a full
// iteration earlier, so no load latency sits on the critical path.
__global__ __launch_bounds__(256, 3)
void fa_main(const float* __restrict__ Q,
             const unsigned short* __restrict__ Kb,
             const unsigned short* __restrict__ Vtb,
             float* __restrict__ O, float qs) {
    const int x  = blockIdx.x & 7;
    const int t  = blockIdx.x >> 3;
    const int bh = x + 8 * (t % 3);
    const int qt = t / 3;
    const int q0 = qt * TQ;

    __shared__ __align__(16) unsigned char SH[16896];
    unsigned short* QS = (unsigned short*)SH;              // prologue only
    float* ORed = (float*)SH;                              // 64x64 f32 (epilogue)
    float* Lsum = (float*)(SH + 16384);                    // 64 f32
    float* Linv = (float*)(SH + 16640);                    // 64 f32

    const int tid  = threadIdx.x;
    const int w    = tid >> 6;
    const int mt   = w >> 1;
    const int nt   = w & 1;
    const int lane = tid & 63;
    const int l31  = lane & 31;
    const int hi   = lane >> 5;

    const float* Qh = Q + ((size_t)bh * SEQ + q0) * HD;

    // ---- prologue: Q (fp32 -> scaled bf16) -> QS; extract B-fragments ----
    #pragma unroll
    for (int u = 0; u < 4; ++u) {
        int idx = u * 1024 + tid * 4;
        int r = idx >> 6, col = idx & 63;
        float4 a = *(const float4*)&Qh[idx];
        uint2 pk = { pack2bf(a.x * qs, a.y * qs), pack2bf(a.z * qs, a.w * qs) };
        *(uint2*)&QS[tile_off(r, col >> 3) + (col & 7)] = pk;
    }
    __syncthreads();
    bf16x8 qf[4];
    #pragma unroll
    for (int s = 0; s < 4; ++s)
        qf[s] = *(const bf16x8*)&QS[tile_off(mt * 32 + l31, s * 2 + hi)];
    __syncthreads();   // all waves extracted qf; ORed overlay safe after this

    // ---- per-lane fragment-linear bases (advance 4096 shorts per tile) ----
    const unsigned short* kB = Kb  + ((size_t)bh * 32 * 2 + nt) * 2048 + lane * 8;
    const unsigned short* vB = Vtb + (size_t)bh * 32 * 4096
                                   + (size_t)(nt * 2) * 1024 + hi * 512 + l31 * 8;

    f32x16 o[2];
    o[0] = (f32x16)(0.f);
    o[1] = (f32x16)(0.f);
    float lsum = 0.f;

    // deferred finish: exp2 + pack + PV + lsum (register-only)
    auto FIN = [&](const f32x16& sp, const bf16x8 (&vp)[2][2]) {
        float e0[8], e1[8];
        #pragma unroll
        for (int r = 0; r < 8; ++r) e0[r] = EXP2F(sp[r]);
        #pragma unroll
        for (int r = 0; r < 8; ++r) e1[r] = EXP2F(sp[8 + r]);
        union { u32x4 d; bf16x8 h; } pu0, pu1;
        pu0.d = (u32x4){ pack2bf(e0[0], e0[1]), pack2bf(e0[2], e0[3]),
                         pack2bf(e0[4], e0[5]), pack2bf(e0[6], e0[7]) };
        pu1.d = (u32x4){ pack2bf(e1[0], e1[1]), pack2bf(e1[2], e1[3]),
                         pack2bf(e1[4], e1[5]), pack2bf(e1[6], e1[7]) };
        bf16x8 pf0 = pu0.h, pf1 = pu1.h;
        __builtin_amdgcn_s_setprio(1);
        o[0] = __builtin_amdgcn_mfma_f32_32x32x16_bf16(pf0, vp[0][0], o[0], 0, 0, 0);
        o[1] = __builtin_amdgcn_mfma_f32_32x32x16_bf16(pf0, vp[1][0], o[1], 0, 0, 0);
        o[0] = __builtin_amdgcn_mfma_f32_32x32x16_bf16(pf1, vp[0][1], o[0], 0, 0, 0);
        o[1] = __builtin_amdgcn_mfma_f32_32x32x16_bf16(pf1, vp[1][1], o[1], 0, 0, 0);
        __builtin_amdgcn_s_setprio(0);
        float t0 = ((e0[0] + e0[1]) + (e0[2] + e0[3]))
                 + ((e0[4] + e0[5]) + (e0[6] + e0[7]));
        float t1 = ((e1[0] + e1[1]) + (e1[2] + e1[3]))
                 + ((e1[4] + e1[5]) + (e1[6] + e1[7]));
        lsum += t0 + t1;
    };

    // pipeline state: K(t) fragments, V(t-1) fragments, S(t-1) scores
    bf16x8 kfc[4];
    bf16x8 vfp[2][2];
    f32x16 scp;

    // ---- prologue loads: K(0), V(0) ----
    #pragma unroll
    for (int s = 0; s < 4; ++s) kfc[s] = *(const bf16x8*)(kB + s * 512);
    #pragma unroll
    for (int dt = 0; dt < 2; ++dt)
        #pragma unroll
        for (int ks = 0; ks < 2; ++ks)
            vfp[dt][ks] = *(const bf16x8*)(vB + ks * 1024 + dt * 256);

    // ---- peeled iteration 0: load K(1); QK(0) ----
    {
        bf16x8 kn[4];
        #pragma unroll
        for (int s = 0; s < 4; ++s) kn[s] = *(const bf16x8*)(kB + 4096 + s * 512);
        f32x16 sc = (f32x16)(0.f);
        __builtin_amdgcn_s_setprio(1);
        #pragma unroll
        for (int s = 0; s < 4; ++s)
            sc = __builtin_amdgcn_mfma_f32_32x32x16_bf16(kfc[s], qf[s], sc, 0, 0, 0);
        __builtin_amdgcn_s_setprio(0);
        scp = sc;
        #pragma unroll
        for (int s = 0; s < 4; ++s) kfc[s] = kn[s];
    }

    // ---- main loop (no barriers): iter t = {load K(t+1),V(t) -> FIN(t-1) ->
    //                                          QK(t) -> rotate} ----
    #pragma unroll 2
    for (int it = 1; it < NIT; ++it) {
        const unsigned short* vT = vB + (size_t)it * 4096;

        // V(t) for next iter's FIN (1-iter cover)
        bf16x8 vn[2][2];
        #pragma unroll
        for (int dt = 0; dt < 2; ++dt)
            #pragma unroll
            for (int ks = 0; ks < 2; ++ks)
                vn[dt][ks] = *(const bf16x8*)(vT + ks * 1024 + dt * 256);
        // K(t+1) for next iter's QK (1-iter cover)
        bf16x8 kn[4];
        if (it + 1 < NIT) {
            const unsigned short* kT = kB + (size_t)(it + 1) * 4096;
            #pragma unroll
            for (int s = 0; s < 4; ++s) kn[s] = *(const bf16x8*)(kT + s * 512);
        }

        // FIN(t-1): register-only
        FIN(scp, vfp);

        // QK(t) on fragments loaded last iteration
        f32x16 scc = (f32x16)(0.f);
        __builtin_amdgcn_s_setprio(1);
        #pragma unroll
        for (int s = 0; s < 4; ++s)
            scc = __builtin_amdgcn_mfma_f32_32x32x16_bf16(kfc[s], qf[s], scc, 0, 0, 0);
        __builtin_amdgcn_s_setprio(0);

        scp = scc;
        #pragma unroll
        for (int dt = 0; dt < 2; ++dt)
            #pragma unroll
            for (int ks = 0; ks < 2; ++ks)
                vfp[dt][ks] = vn[dt][ks];
        if (it + 1 < NIT) {
            #pragma unroll
            for (int s = 0; s < 4; ++s) kfc[s] = kn[s];
        }
    }

    // ---- tail: finish the last tile ----
    FIN(scp, vfp);

    // ---- epilogue: combine nt partials (O and lsum), normalize, store ----
    lsum += __shfl_xor(lsum, 32, 64);

    if (nt == 1) {
        if (lane < 32) Lsum[mt * 32 + lane] = lsum;
        #pragma unroll
        for (int dt = 0; dt < 2; ++dt) {
            const int d = dt * 32 + l31;
            #pragma unroll
            for (int g = 0; g < 4; ++g) {
                const int m0 = mt * 32 + 8 * g + 4 * hi;
                const int ph = (m0 >> 2) ^ (d & 15);
                float4 v = { o[dt][4*g+0], o[dt][4*g+1], o[dt][4*g+2], o[dt][4*g+3] };
                *(float4*)&ORed[d * 64 + ph * 4] = v;
            }
        }
    }
    __syncthreads();

    if (nt == 0) {
        float ltot = lsum + Lsum[mt * 32 + l31];
        if (lane < 32) Linv[mt * 32 + lane] = 1.0f / ltot;
        float* Oh = O + ((size_t)bh * SEQ + q0) * HD;
        #pragma unroll
        for (int dt = 0; dt < 2; ++dt) {
            const int d = dt * 32 + l31;
            #pragma unroll
            for (int g = 0; g < 4; ++g) {
                const int m0 = mt * 32 + 8 * g + 4 * hi;
                const int ph = (m0 >> 2) ^ (d & 15);
                float4 part = *(const float4*)&ORed[d * 64 + ph * 4];
                float4 inv4 = *(const float4*)&Linv[m0];
                const float* pp = (const float*)&part;
                const float* ii = (const float*)&inv4;
                #pragma unroll
                for (int j = 0; j < 4; ++j)
                    Oh[(size_t)(m0 + j) * HD + d] = (o[dt][4*g+j] + pp[j]) * ii[j];
            }
        }
    }
}

// ---------------- fallback (no-workspace) kernel ----------------
#define PAD 8
#define LSTR (HD + PAD)

__global__ __launch_bounds__(256)
void fa_fwd_fb(const float* __restrict__ Q, const float* __restrict__ K,
               const float* __restrict__ V, float* __restrict__ O) {
    const int x  = blockIdx.x & 7;
    const int t  = blockIdx.x >> 3;
    const int bh = x + 8 * (t % 3);
    const int qt = t / 3;
    const int q0 = qt * TQ;
    const long base = (long)bh * SEQ * HD;

    __shared__ unsigned short Qs[TQ][LSTR];
    __shared__ unsigned short Ks2[64][LSTR];
    __shared__ unsigned short Vt[HD][64 + PAD];
    __shared__ unsigned short Ps2[4][16][LSTR];

    const int tid  = threadIdx.x;
    const int wave = tid >> 6;
    const int lane = tid & 63;
    const int col  = lane & 15;
    const int quad = lane >> 4;
    const int m0   = wave * 16;

    #pragma unroll
    for (int i = 0; i < 4; ++i) {
        int idx = tid + 256 * i;
        int row = idx >> 4;
        int c4  = (idx & 15) * 4;
        float4 v = *(const float4*)&Q[base + (long)(q0 + row) * HD + c4];
        ushort4 b = { f2bf(v.x), f2bf(v.y), f2bf(v.z), f2bf(v.w) };
        *(ushort4*)&Qs[row][c4] = b;
    }
    __syncthreads();

    bf16x8 aq0 = *(const bf16x8*)&Qs[m0 + col][quad * 8];
    bf16x8 aq1 = *(const bf16x8*)&Qs[m0 + col][32 + quad * 8];

    f32x4 o0 = {0.f,0.f,0.f,0.f}, o1 = o0, o2 = o0, o3 = o0;
    float l[4] = {0.f, 0.f, 0.f, 0.f};
    const float scale = 0.022097086912079608f;

    for (int kv0 = 0; kv0 < SEQ; kv0 += 64) {
        __syncthreads();
        #pragma unroll
        for (int i = 0; i < 4; ++i) {
            int idx = tid + 256 * i;
            int row = idx >> 4;
            int c4  = (idx & 15) * 4;
            float4 kv = *(const float4*)&K[base + (long)(kv0 + row) * HD + c4];
            ushort4 kb = { f2bf(kv.x), f2bf(kv.y), f2bf(kv.z), f2bf(kv.w) };
            *(ushort4*)&Ks2[row][c4] = kb;
            float4 vv = *(const float4*)&V[base + (long)(kv0 + row) * HD + c4];
            Vt[c4 + 0][row] = f2bf(vv.x);
            Vt[c4 + 1][row] = f2bf(vv.y);
            Vt[c4 + 2][row] = f2bf(vv.z);
            Vt[c4 + 3][row] = f2bf(vv.w);
        }
        __syncthreads();

        f32x4 sc[4];
        #pragma unroll
        for (int n = 0; n < 4; ++n) {
            bf16x8 b0 = *(const bf16x8*)&Ks2[n * 16 + col][quad * 8];
            bf16x8 b1 = *(const bf16x8*)&Ks2[n * 16 + col][32 + quad * 8];
            f32x4 acc = {0.f,0.f,0.f,0.f};
            acc = __builtin_amdgcn_mfma_f32_16x16x32_bf16(aq0, b0, acc, 0, 0, 0);
            acc = __builtin_amdgcn_mfma_f32_16x16x32_bf16(aq1, b1, acc, 0, 0, 0);
            sc[n] = acc;
        }

        float tsum[4] = {0.f, 0.f, 0.f, 0.f};
        #pragma unroll
        for (int n = 0; n < 4; ++n) {
            #pragma unroll
            for (int r = 0; r < 4; ++r) {
                float p = __expf(sc[n][r] * scale);
                tsum[r] += p;
                Ps2[wave][quad * 4 + r][n * 16 + col] = f2bf(p);
            }
        }
        #pragma unroll
        for (int off = 1; off < 16; off <<= 1) {
            #pragma unroll
            for (int r = 0; r < 4; ++r) tsum[r] += __shfl_xor(tsum[r], off, 64);
        }
        #pragma unroll
        for (int r = 0; r < 4; ++r) l[r] += tsum[r];

        bf16x8 ap0 = *(const bf16x8*)&Ps2[wave][col][quad * 8];
        bf16x8 ap1 = *(const bf16x8*)&Ps2[wave][col][32 + quad * 8];
        #pragma unroll
        for (int n = 0; n < 4; ++n) {
            bf16x8 b0 = *(const bf16x8*)&Vt[n * 16 + col][quad * 8];
            bf16x8 b1 = *(const bf16x8*)&Vt[n * 16 + col][32 + quad * 8];
            f32x4* op = (n == 0) ? &o0 : (n == 1) ? &o1 : (n == 2) ? &o2 : &o3;
            *op = __builtin_amdgcn_mfma_f32_16x16x32_bf16(ap0, b0, *op, 0, 0, 0);
            *op = __builtin_amdgcn_mfma_f32_16x16x32_bf16(ap1, b1, *op, 0, 0, 0);
        }
    }

    float inv[4];
    #pragma unroll
    for (int r = 0; r < 4; ++r) inv[r] = 1.0f / l[r];
    #pragma unroll
    for (int r = 0; r < 4; ++r) {
        long row = base + (long)(q0 + m0 + quad * 4 + r) * HD;
        O[row +  0 + col] = o0[r] * inv[r];
        O[row + 16 + col] = o1[r] * inv[r];
        O[row + 32 + col] = o2[r] * inv[r];
        O[row + 48 + col] = o3[r] * inv[r];
    }
}

extern "C" void kernel_launch(void* const* d_in, const int* in_sizes, int n_in,
                              void* d_out, int out_size, void* d_ws, size_t ws_size,
                              hipStream_t stream) {
    const float* Q = (const float*)d_in[0];
    const float* K = (const float*)d_in[1];
    const float* V = (const float*)d_in[2];
    float* O = (float*)d_out;

    const size_t tensorElems = (size_t)NHEADS * SEQ * HD;
    const size_t need = 2 * tensorElems * sizeof(unsigned short);

    if (ws_size >= need) {
        unsigned short* Kb  = (unsigned short*)d_ws;
        unsigned short* Vtb = Kb + tensorElems;
        const float qs = (float)(1.4426950408889634 / sqrt(2048.0));  // log2e/sqrt(S)
        prep_kv<<<dim3(NHEADS * (SEQ / 64)), dim3(256), 0, stream>>>(K, V, Kb, Vtb);
        fa_main<<<dim3(NHEADS * (SEQ / TQ)), dim3(256), 0, stream>>>(Q, Kb, Vtb, O, qs);
    } else {
        fa_fwd_fb<<<dim3(NHEADS * (SEQ / TQ)), dim3(256), 0, stream>>>(Q, K, V, O);
    }
}